// Round 2
// baseline (1519.699 us; speedup 1.0000x reference)
//
#include <hip/hip_runtime.h>
#include <math.h>

typedef unsigned short u16;
typedef short s16x8 __attribute__((ext_vector_type(8)));
typedef float f32x4 __attribute__((ext_vector_type(4)));

#define GLOAD16(gp, lp)                                                        \
  __builtin_amdgcn_global_load_lds(                                            \
      (const __attribute__((address_space(1))) void*)(gp),                     \
      (__attribute__((address_space(3))) void*)(lp), 16, 0, 0)

__device__ __forceinline__ u16 f2bf(float f) {
  union { float f; unsigned u; } v; v.f = f;
  unsigned r = v.u + 0x7fffu + ((v.u >> 16) & 1u);  // RNE
  return (u16)(r >> 16);
}

// ---------------- kernel 1: x fp32 -> bf16 ----------------
__global__ __launch_bounds__(256) void cvt_x_kernel(const float* __restrict__ in,
                                                    u16* __restrict__ out) {
  size_t i = ((size_t)blockIdx.x * 256 + threadIdx.x) * 8;
  float4 a = *(const float4*)(in + i);
  float4 b = *(const float4*)(in + i + 4);
  s16x8 v;
  v[0] = (short)f2bf(a.x); v[1] = (short)f2bf(a.y);
  v[2] = (short)f2bf(a.z); v[3] = (short)f2bf(a.w);
  v[4] = (short)f2bf(b.x); v[5] = (short)f2bf(b.y);
  v[6] = (short)f2bf(b.z); v[7] = (short)f2bf(b.w);
  *(s16x8*)(out + i) = v;
}

// ------- kernel 2: transpose+cvt. mats 0-3 (g/u) write into interleaved GU:
// GU row for logical f-col, type t: (f>>4)*32 + t*16 + (f&15). mats 4,5 plain.
__global__ __launch_bounds__(256) void transpose_cvt_kernel(
    const float* __restrict__ in0, const float* __restrict__ in1,
    const float* __restrict__ in2, const float* __restrict__ in3,
    const float* __restrict__ in4, const float* __restrict__ in5,
    u16* __restrict__ o01, u16* __restrict__ o23,
    u16* __restrict__ o4, u16* __restrict__ o5) {
  __shared__ float s[64 * 65];
  const int mat = blockIdx.y;
  const float* in; u16* out;
  switch (mat) {
    case 0: in = in0; out = o01; break;
    case 1: in = in1; out = o01; break;
    case 2: in = in2; out = o23; break;
    case 3: in = in3; out = o23; break;
    case 4: in = in4; out = o4; break;
    default: in = in5; out = o5; break;
  }
  const int R = (mat < 4) ? 4096 : 11008;   // input rows = output stride
  const int C = (mat < 4) ? 11008 : 4096;   // input cols
  const int nTc = C >> 6;
  const int tr = blockIdx.x / nTc, tc = blockIdx.x - tr * nTc;
  const int r0 = tr << 6, c0 = tc << 6;
  const int t = threadIdx.x;
#pragma unroll
  for (int p = 0; p < 4; ++p) {
    const int lr = p * 16 + (t >> 4);
    const int lc = (t & 15) * 4;
    float4 v = *(const float4*)(in + (size_t)(r0 + lr) * C + (c0 + lc));
    float* sp = &s[lr * 65 + lc];
    sp[0] = v.x; sp[1] = v.y; sp[2] = v.z; sp[3] = v.w;
  }
  __syncthreads();
#pragma unroll
  for (int q = 0; q < 2; ++q) {
    const int oc = q * 32 + (t >> 3);
    const int orr = (t & 7) * 8;
    s16x8 v;
#pragma unroll
    for (int i = 0; i < 8; ++i) v[i] = (short)f2bf(s[(orr + i) * 65 + oc]);
    const int f = c0 + oc;
    size_t orow;
    if (mat < 4) orow = (size_t)((f >> 4) << 5) + ((mat & 1) << 4) + (f & 15);
    else         orow = (size_t)f;
    *(s16x8*)(out + orow * R + (r0 + orr)) = v;
  }
}

// ---------------- 256x256 8-phase GEMM (BK=64, 8 waves 2Mx4N) ----------------
// A [M][K] bf16 k-contig; B [N][K] bf16 k-contig (row n = output col n).
// Wave (wm,wn): m-frags f=0..7 at row mh*128 + wm*64 + (f&3)*16 (mh=f>>2);
//               n-frags g=0..3 at col nh*128 + wn*32 + (g&1)*16 (nh=g>>1).
// LDS: [2 buf][2 half][128 rows][128B], 16B-chunk XOR swizzle pos = c ^ (row&7)
// applied on pre-swizzled global source (global_load_lds writes linearly).
// EPI 0: fused silu(gate)*up -> bf16 H (interleaved-GU column mapping)
// EPI 1: fp32 store to out.
template <int KB, int EPI>
__global__ __launch_bounds__(512, 1) void gemm256(
    const u16* __restrict__ A, const u16* __restrict__ Bl,
    const u16* __restrict__ Bv, const int* __restrict__ tt,
    void* __restrict__ OutP) {
  constexpr int NK = KB / 128;  // K-tiles of 64
  constexpr int L = NK / 2;     // iterations (2 K-tiles each)
  __shared__ u16 sA[2][2][128][64];
  __shared__ u16 sB[2][2][128][64];

  const int nwg = gridDim.x;
  const int bid = blockIdx.x;
  const int wg = (bid & 7) * (nwg >> 3) + (bid >> 3);  // bijective XCD swizzle
  const int mT = wg & 15;
  const int nT = wg >> 4;

  const int t = threadIdx.x;
  const int lane = t & 63;
  const int rlo = lane & 15;
  const int hi = lane >> 4;
  const int wn = (t >> 6) & 3;
  const int wm = (t >> 8) & 1;

  const int side = tt[mT << 8];
  const u16* B = side ? Bl : Bv;

  // staging source addresses (pre-swizzled global, rule #21)
  const int rowq = t >> 3;  // 0..63
  const int gsw = ((t & 7) ^ (rowq & 7)) << 4;
  const char* srcA = (const char*)A + (size_t)(mT * 256 + rowq) * KB + gsw;
  const char* srcB = (const char*)B + (size_t)(nT * 256 + rowq) * KB + gsw;
  char* ldsA = (char*)&sA[0][0][0][0];
  char* ldsB = (char*)&sB[0][0][0][0];
  const int woff = (t & 448) << 4;  // wave-uniform LDS base, HW adds lane*16

#define STG_A(d, h, kt)                                                        \
  do {                                                                         \
    GLOAD16(srcA + (size_t)((h) * 128) * KB + (kt) * 128,                      \
            ldsA + (d) * 32768 + (h) * 16384 + woff);                          \
    GLOAD16(srcA + (size_t)((h) * 128 + 64) * KB + (kt) * 128,                 \
            ldsA + (d) * 32768 + (h) * 16384 + 8192 + woff);                   \
  } while (0)
#define STG_B(d, h, kt)                                                        \
  do {                                                                         \
    GLOAD16(srcB + (size_t)((h) * 128) * KB + (kt) * 128,                      \
            ldsB + (d) * 32768 + (h) * 16384 + woff);                          \
    GLOAD16(srcB + (size_t)((h) * 128 + 64) * KB + (kt) * 128,                 \
            ldsB + (d) * 32768 + (h) * 16384 + 8192 + woff);                   \
  } while (0)

  const int cxa = (hi ^ (rlo & 7)) << 4;        // k-chunk 0..3 (ks=0)
  const int cxb = ((4 + hi) ^ (rlo & 7)) << 4;  // k-chunk 4..7 (ks=1)
  const int arow = (wm * 64 + rlo) * 128;
  const int brow = (wn * 32 + rlo) * 128;

  s16x8 af[4][2], bf[2][2];
  f32x4 acc[8][4];
  const f32x4 z = {0.f, 0.f, 0.f, 0.f};
#pragma unroll
  for (int i = 0; i < 8; ++i)
#pragma unroll
    for (int j = 0; j < 4; ++j) acc[i][j] = z;

#define LDA(d, mh)                                                             \
  do {                                                                         \
    _Pragma("unroll") for (int fi = 0; fi < 4; ++fi) {                         \
      const char* p = ldsA + (d) * 32768 + (mh) * 16384 + arow + fi * 2048;    \
      af[fi][0] = *(const s16x8*)(p + cxa);                                    \
      af[fi][1] = *(const s16x8*)(p + cxb);                                    \
    }                                                                          \
  } while (0)
#define LDB(d, nh)                                                             \
  do {                                                                         \
    _Pragma("unroll") for (int gi = 0; gi < 2; ++gi) {                         \
      const char* p = ldsB + (d) * 32768 + (nh) * 16384 + brow + gi * 2048;    \
      bf[gi][0] = *(const s16x8*)(p + cxa);                                    \
      bf[gi][1] = *(const s16x8*)(p + cxb);                                    \
    }                                                                          \
  } while (0)
#define MFMA16(mh, nh)                                                         \
  do {                                                                         \
    __builtin_amdgcn_s_setprio(1);                                             \
    _Pragma("unroll") for (int fi = 0; fi < 4; ++fi)                           \
        _Pragma("unroll") for (int gi = 0; gi < 2; ++gi) {                     \
      acc[(mh)*4 + fi][(nh)*2 + gi] = __builtin_amdgcn_mfma_f32_16x16x32_bf16( \
          af[fi][0], bf[gi][0], acc[(mh)*4 + fi][(nh)*2 + gi], 0, 0, 0);       \
      acc[(mh)*4 + fi][(nh)*2 + gi] = __builtin_amdgcn_mfma_f32_16x16x32_bf16( \
          af[fi][1], bf[gi][1], acc[(mh)*4 + fi][(nh)*2 + gi], 0, 0, 0);       \
    }                                                                          \
    __builtin_amdgcn_s_setprio(0);                                             \
  } while (0)
#define SBAR() __builtin_amdgcn_s_barrier()
#define VMCNT4() do { asm volatile("s_waitcnt vmcnt(4)" ::: "memory");         \
                      __builtin_amdgcn_sched_barrier(0); } while (0)
#define VMCNT0() do { asm volatile("s_waitcnt vmcnt(0)" ::: "memory");         \
                      __builtin_amdgcn_sched_barrier(0); } while (0)

  // prologue: T0 fully + T1 {B-h0, A-h1}; drain T0, keep T1's 4 in flight
  STG_A(0, 0, 0); STG_A(0, 1, 0); STG_B(0, 0, 0); STG_B(0, 1, 0);
  STG_B(1, 0, 1); STG_A(1, 1, 1);
  VMCNT4();
  SBAR();

  for (int it = 0; it < L - 1; ++it) {
    const int T = 2 * it;
    // P1: quad(0,0) buf0 | stage A-h0(T+1),B-h1(T+1)->buf1
    LDA(0, 0); LDB(0, 0);
    STG_A(1, 0, T + 1); STG_B(1, 1, T + 1);
    SBAR(); MFMA16(0, 0); SBAR();
    // P2: quad(1,0)
    LDA(0, 1);
    SBAR(); MFMA16(1, 0); SBAR();
    // P3: quad(1,1) | stage B-h0(T+2)->buf0
    LDB(0, 1);
    STG_B(0, 0, T + 2);
    SBAR(); MFMA16(1, 1); SBAR();
    // P4: quad(0,1) | stage A-h1(T+2)->buf0 | checkpoint
    LDA(0, 0);
    STG_A(0, 1, T + 2);
    SBAR(); MFMA16(0, 1);
    VMCNT4(); SBAR();
    // P5: quad(0,0) buf1 | stage A-h0(T+2),B-h1(T+2)->buf0
    LDA(1, 0); LDB(1, 0);
    STG_A(0, 0, T + 2); STG_B(0, 1, T + 2);
    SBAR(); MFMA16(0, 0); SBAR();
    // P6
    LDA(1, 1);
    SBAR(); MFMA16(1, 0); SBAR();
    // P7 | stage B-h0(T+3)->buf1
    LDB(1, 1);
    STG_B(1, 0, T + 3);
    SBAR(); MFMA16(1, 1); SBAR();
    // P8 | stage A-h1(T+3)->buf1 | checkpoint
    LDA(1, 0);
    STG_A(1, 1, T + 3);
    SBAR(); MFMA16(0, 1);
    VMCNT4(); SBAR();
  }
  // final iteration (T = NK-2): only P1 stages; drain at P4 checkpoint
  {
    const int T = NK - 2;
    LDA(0, 0); LDB(0, 0);
    STG_A(1, 0, T + 1); STG_B(1, 1, T + 1);
    SBAR(); MFMA16(0, 0); SBAR();
    LDA(0, 1);
    SBAR(); MFMA16(1, 0); SBAR();
    LDB(0, 1);
    SBAR(); MFMA16(1, 1); SBAR();
    LDA(0, 0);
    SBAR(); MFMA16(0, 1);
    VMCNT0(); SBAR();
    LDA(1, 0); LDB(1, 0);
    SBAR(); MFMA16(0, 0); SBAR();
    LDA(1, 1);
    SBAR(); MFMA16(1, 0); SBAR();
    LDB(1, 1);
    SBAR(); MFMA16(1, 1); SBAR();
    LDA(1, 0);
    SBAR(); MFMA16(0, 1);
  }

  // ---------------- epilogue ----------------
  if (EPI == 0) {
    u16* H = (u16*)OutP;
#pragma unroll
    for (int mh = 0; mh < 2; ++mh)
#pragma unroll
      for (int fi = 0; fi < 4; ++fi) {
        const int row0 = mT * 256 + mh * 128 + wm * 64 + fi * 16 + hi * 4;
#pragma unroll
        for (int nh = 0; nh < 2; ++nh) {
          const int fc = nT * 128 + (nh * 4 + wn) * 16 + rlo;
          const f32x4 g = acc[mh * 4 + fi][nh * 2 + 0];
          const f32x4 u = acc[mh * 4 + fi][nh * 2 + 1];
#pragma unroll
          for (int r = 0; r < 4; ++r) {
            const float gv = g[r];
            const float hv = gv / (1.f + __expf(-gv)) * u[r];
            H[(size_t)(row0 + r) * 11008 + fc] = f2bf(hv);
          }
        }
      }
  } else {
    float* O = (float*)OutP;
#pragma unroll
    for (int mh = 0; mh < 2; ++mh)
#pragma unroll
      for (int fi = 0; fi < 4; ++fi) {
        const int row0 = mT * 256 + mh * 128 + wm * 64 + fi * 16 + hi * 4;
#pragma unroll
        for (int nh = 0; nh < 2; ++nh)
#pragma unroll
          for (int gi = 0; gi < 2; ++gi) {
            const int col = nT * 256 + nh * 128 + wn * 32 + gi * 16 + rlo;
            const f32x4 a = acc[mh * 4 + fi][nh * 2 + gi];
#pragma unroll
            for (int r = 0; r < 4; ++r)
              O[(size_t)(row0 + r) * 4096 + col] = a[r];
          }
      }
  }
#undef STG_A
#undef STG_B
#undef LDA
#undef LDB
#undef MFMA16
#undef SBAR
#undef VMCNT4
#undef VMCNT0
}

extern "C" void kernel_launch(void* const* d_in, const int* in_sizes, int n_in,
                              void* d_out, int out_size, void* d_ws, size_t ws_size,
                              hipStream_t stream) {
  (void)in_sizes; (void)n_in; (void)out_size; (void)ws_size;
  const float* x  = (const float*)d_in[0];
  const int*   tt = (const int*)d_in[1];
  const float* lg = (const float*)d_in[2];
  const float* lu = (const float*)d_in[3];
  const float* ld = (const float*)d_in[4];
  const float* vg = (const float*)d_in[5];
  const float* vu = (const float*)d_in[6];
  const float* vd = (const float*)d_in[7];

  u16* ws  = (u16*)d_ws;
  u16* xbf = ws;                        // 4096*4096            = 16,777,216
  u16* GUl = xbf + 16777216;            // 22016*4096           = 90,177,536
  u16* GUv = GUl + 90177536;
  u16* ldT = GUv + 90177536;            // 4096*11008           = 45,088,768
  u16* vdT = ldT + 45088768;
  u16* hbuf = vdT + 45088768;           // 4096*11008
  // total: 332,398,592 u16 = ~665 MB

  cvt_x_kernel<<<dim3(8192), dim3(256), 0, stream>>>(x, xbf);
  transpose_cvt_kernel<<<dim3(11008, 6), dim3(256), 0, stream>>>(
      lg, lu, vg, vu, ld, vd, GUl, GUv, ldT, vdT);
  // gate+up fused GEMM: M=4096 (16 mT), N=22016 (86 nT) -> 1376 blocks
  gemm256<8192, 0><<<dim3(1376), dim3(512), 0, stream>>>(xbf, GUl, GUv, tt, hbuf);
  // down GEMM: M=4096, N=4096, K=11008 -> 256 blocks (1/CU)
  gemm256<22016, 1><<<dim3(256), dim3(512), 0, stream>>>(hbuf, ldT, vdT, tt, d_out);
}

// Round 3
// 1474.072 us; speedup vs baseline: 1.0310x; 1.0310x over previous
//
#include <hip/hip_runtime.h>
#include <math.h>

typedef unsigned short u16;
typedef short s16x8 __attribute__((ext_vector_type(8)));
typedef float f32x4 __attribute__((ext_vector_type(4)));

#define GLOAD16(gp, lp)                                                        \
  __builtin_amdgcn_global_load_lds(                                            \
      (const __attribute__((address_space(1))) void*)(gp),                     \
      (__attribute__((address_space(3))) void*)(lp), 16, 0, 0)

__device__ __forceinline__ u16 f2bf(float f) {
  union { float f; unsigned u; } v; v.f = f;
  unsigned r = v.u + 0x7fffu + ((v.u >> 16) & 1u);  // RNE
  return (u16)(r >> 16);
}

// ---------------- kernel 1: x fp32 -> bf16 ----------------
__global__ __launch_bounds__(256) void cvt_x_kernel(const float* __restrict__ in,
                                                    u16* __restrict__ out) {
  size_t i = ((size_t)blockIdx.x * 256 + threadIdx.x) * 8;
  float4 a = *(const float4*)(in + i);
  float4 b = *(const float4*)(in + i + 4);
  s16x8 v;
  v[0] = (short)f2bf(a.x); v[1] = (short)f2bf(a.y);
  v[2] = (short)f2bf(a.z); v[3] = (short)f2bf(a.w);
  v[4] = (short)f2bf(b.x); v[5] = (short)f2bf(b.y);
  v[6] = (short)f2bf(b.z); v[7] = (short)f2bf(b.w);
  *(s16x8*)(out + i) = v;
}

// ------- kernel 2: transpose+cvt. mats 0-3 (g/u) write into interleaved GU:
// GU row for logical f-col, type t: (f>>4)*32 + t*16 + (f&15). mats 4,5 plain.
__global__ __launch_bounds__(256) void transpose_cvt_kernel(
    const float* __restrict__ in0, const float* __restrict__ in1,
    const float* __restrict__ in2, const float* __restrict__ in3,
    const float* __restrict__ in4, const float* __restrict__ in5,
    u16* __restrict__ o01, u16* __restrict__ o23,
    u16* __restrict__ o4, u16* __restrict__ o5) {
  __shared__ float s[64 * 65];
  const int mat = blockIdx.y;
  const float* in; u16* out;
  switch (mat) {
    case 0: in = in0; out = o01; break;
    case 1: in = in1; out = o01; break;
    case 2: in = in2; out = o23; break;
    case 3: in = in3; out = o23; break;
    case 4: in = in4; out = o4; break;
    default: in = in5; out = o5; break;
  }
  const int R = (mat < 4) ? 4096 : 11008;   // input rows = output stride
  const int C = (mat < 4) ? 11008 : 4096;   // input cols
  const int nTc = C >> 6;
  const int tr = blockIdx.x / nTc, tc = blockIdx.x - tr * nTc;
  const int r0 = tr << 6, c0 = tc << 6;
  const int t = threadIdx.x;
#pragma unroll
  for (int p = 0; p < 4; ++p) {
    const int lr = p * 16 + (t >> 4);
    const int lc = (t & 15) * 4;
    float4 v = *(const float4*)(in + (size_t)(r0 + lr) * C + (c0 + lc));
    float* sp = &s[lr * 65 + lc];
    sp[0] = v.x; sp[1] = v.y; sp[2] = v.z; sp[3] = v.w;
  }
  __syncthreads();
#pragma unroll
  for (int q = 0; q < 2; ++q) {
    const int oc = q * 32 + (t >> 3);
    const int orr = (t & 7) * 8;
    s16x8 v;
#pragma unroll
    for (int i = 0; i < 8; ++i) v[i] = (short)f2bf(s[(orr + i) * 65 + oc]);
    const int f = c0 + oc;
    size_t orow;
    if (mat < 4) orow = (size_t)((f >> 4) << 5) + ((mat & 1) << 4) + (f & 15);
    else         orow = (size_t)f;
    *(s16x8*)(out + orow * R + (r0 + orr)) = v;
  }
}

// ---------------- 256x256 8-phase GEMM (BK=64, 8 waves 2Mx4N) ----------------
// m201-faithful schedule: 1 half-tile staged per phase, vmcnt(6) at P4/P8,
// plain lgkmcnt waits, no compiler fences. 2 K-tiles per iteration.
template <int KB, int EPI>
__global__ __launch_bounds__(512, 1) void gemm256(
    const u16* __restrict__ A, const u16* __restrict__ Bl,
    const u16* __restrict__ Bv, const int* __restrict__ tt,
    void* __restrict__ OutP) {
  constexpr int NK = KB / 128;  // K-tiles of 64
  constexpr int L = NK / 2;     // iterations (2 K-tiles each)
  __shared__ u16 sA[2][2][128][64];
  __shared__ u16 sB[2][2][128][64];

  const int nwg = gridDim.x;
  const int bid = blockIdx.x;
  const int wg = (bid & 7) * (nwg >> 3) + (bid >> 3);  // bijective XCD swizzle
  const int mT = wg & 15;
  const int nT = wg >> 4;

  const int t = threadIdx.x;
  const int lane = t & 63;
  const int rlo = lane & 15;
  const int hi = lane >> 4;
  const int wn = (t >> 6) & 3;
  const int wm = (t >> 8) & 1;

  const int side = tt[mT << 8];
  const u16* B = side ? Bl : Bv;

  // staging source addresses (pre-swizzled global, rule #21)
  const int rowq = t >> 3;  // 0..63
  const int gsw = ((t & 7) ^ (rowq & 7)) << 4;
  const char* srcA = (const char*)A + (size_t)(mT * 256 + rowq) * KB + gsw;
  const char* srcB = (const char*)B + (size_t)(nT * 256 + rowq) * KB + gsw;
  char* ldsA = (char*)&sA[0][0][0][0];
  char* ldsB = (char*)&sB[0][0][0][0];
  const int woff = (t & 448) << 4;  // wave-uniform LDS base, HW adds lane*16

#define STG_A(d, h, kt)                                                        \
  do {                                                                         \
    GLOAD16(srcA + (size_t)((h) * 128) * KB + (kt) * 128,                      \
            ldsA + (d) * 32768 + (h) * 16384 + woff);                          \
    GLOAD16(srcA + (size_t)((h) * 128 + 64) * KB + (kt) * 128,                 \
            ldsA + (d) * 32768 + (h) * 16384 + 8192 + woff);                   \
  } while (0)
#define STG_B(d, h, kt)                                                        \
  do {                                                                         \
    GLOAD16(srcB + (size_t)((h) * 128) * KB + (kt) * 128,                      \
            ldsB + (d) * 32768 + (h) * 16384 + woff);                          \
    GLOAD16(srcB + (size_t)((h) * 128 + 64) * KB + (kt) * 128,                 \
            ldsB + (d) * 32768 + (h) * 16384 + 8192 + woff);                   \
  } while (0)

  const int cxa = (hi ^ (rlo & 7)) << 4;        // k-chunk 0..3 (ks=0)
  const int cxb = ((4 + hi) ^ (rlo & 7)) << 4;  // k-chunk 4..7 (ks=1)
  const int arow = (wm * 64 + rlo) * 128;
  const int brow = (wn * 32 + rlo) * 128;

  s16x8 af[4][2], bf[2][2];
  f32x4 acc[8][4];
  const f32x4 z = {0.f, 0.f, 0.f, 0.f};
#pragma unroll
  for (int i = 0; i < 8; ++i)
#pragma unroll
    for (int j = 0; j < 4; ++j) acc[i][j] = z;

#define LDA(d, mh)                                                             \
  do {                                                                         \
    _Pragma("unroll") for (int fi = 0; fi < 4; ++fi) {                         \
      const char* p = ldsA + (d) * 32768 + (mh) * 16384 + arow + fi * 2048;    \
      af[fi][0] = *(const s16x8*)(p + cxa);                                    \
      af[fi][1] = *(const s16x8*)(p + cxb);                                    \
    }                                                                          \
  } while (0)
#define LDB(d, nh)                                                             \
  do {                                                                         \
    _Pragma("unroll") for (int gi = 0; gi < 2; ++gi) {                         \
      const char* p = ldsB + (d) * 32768 + (nh) * 16384 + brow + gi * 2048;    \
      bf[gi][0] = *(const s16x8*)(p + cxa);                                    \
      bf[gi][1] = *(const s16x8*)(p + cxb);                                    \
    }                                                                          \
  } while (0)
#define MFMA16(mh, nh)                                                         \
  do {                                                                         \
    __builtin_amdgcn_s_setprio(1);                                             \
    _Pragma("unroll") for (int fi = 0; fi < 4; ++fi)                           \
        _Pragma("unroll") for (int gi = 0; gi < 2; ++gi) {                     \
      acc[(mh)*4 + fi][(nh)*2 + gi] = __builtin_amdgcn_mfma_f32_16x16x32_bf16( \
          af[fi][0], bf[gi][0], acc[(mh)*4 + fi][(nh)*2 + gi], 0, 0, 0);       \
      acc[(mh)*4 + fi][(nh)*2 + gi] = __builtin_amdgcn_mfma_f32_16x16x32_bf16( \
          af[fi][1], bf[gi][1], acc[(mh)*4 + fi][(nh)*2 + gi], 0, 0, 0);       \
    }                                                                          \
    __builtin_amdgcn_s_setprio(0);                                             \
  } while (0)
#define SBAR() __builtin_amdgcn_s_barrier()
#define LGKM0() asm volatile("s_waitcnt lgkmcnt(0)")
#define LGKM8() asm volatile("s_waitcnt lgkmcnt(8)")
#define VMCNT6() asm volatile("s_waitcnt vmcnt(6)")
#define VMCNT0() asm volatile("s_waitcnt vmcnt(0)")

  // prologue: tile0 full (8 loads) + tile1 {B-h0, A-h1, B-h1} (6 loads);
  // drain tile0, enter steady state with exactly 6 outstanding.
  STG_A(0, 0, 0); STG_B(0, 0, 0); STG_A(0, 1, 0); STG_B(0, 1, 0);
  STG_B(1, 0, 1); STG_A(1, 1, 1); STG_B(1, 1, 1);
  VMCNT6();
  SBAR();

  for (int it = 0; it < L - 1; ++it) {
    const int T = 2 * it;
    // P1: quad(0,0) buf0 | stage A-h0(T+1)->buf1
    LDA(0, 0); LDB(0, 0);
    STG_A(1, 0, T + 1);
    LGKM8();
    SBAR(); LGKM0(); MFMA16(0, 0); SBAR();
    // P2: quad(1,0) | stage B-h0(T+2)->buf0
    LDA(0, 1);
    STG_B(0, 0, T + 2);
    SBAR(); LGKM0(); MFMA16(1, 0); SBAR();
    // P3: quad(1,1) | stage A-h1(T+2)->buf0
    LDB(0, 1);
    STG_A(0, 1, T + 2);
    SBAR(); LGKM0(); MFMA16(1, 1); SBAR();
    // P4: quad(0,1) | stage B-h1(T+2)->buf0 | checkpoint
    LDA(0, 0);
    STG_B(0, 1, T + 2);
    VMCNT6();
    SBAR(); LGKM0(); MFMA16(0, 1); SBAR();
    // P5: quad(0,0) buf1 | stage A-h0(T+2)->buf0
    LDA(1, 0); LDB(1, 0);
    STG_A(0, 0, T + 2);
    LGKM8();
    SBAR(); LGKM0(); MFMA16(0, 0); SBAR();
    // P6: quad(1,0) | stage B-h0(T+3)->buf1
    LDA(1, 1);
    STG_B(1, 0, T + 3);
    SBAR(); LGKM0(); MFMA16(1, 0); SBAR();
    // P7: quad(1,1) | stage A-h1(T+3)->buf1
    LDB(1, 1);
    STG_A(1, 1, T + 3);
    SBAR(); LGKM0(); MFMA16(1, 1); SBAR();
    // P8: quad(0,1) | stage B-h1(T+3)->buf1 | checkpoint
    LDA(1, 0);
    STG_B(1, 1, T + 3);
    VMCNT6();
    SBAR(); LGKM0(); MFMA16(0, 1); SBAR();
  }
  // tail iteration (T = NK-2): P1 stages last half; drain fully at P4.
  {
    const int T = NK - 2;
    LDA(0, 0); LDB(0, 0);
    STG_A(1, 0, T + 1);
    LGKM8();
    SBAR(); LGKM0(); MFMA16(0, 0); SBAR();
    LDA(0, 1);
    SBAR(); LGKM0(); MFMA16(1, 0); SBAR();
    LDB(0, 1);
    SBAR(); LGKM0(); MFMA16(1, 1); SBAR();
    LDA(0, 0);
    VMCNT0();
    SBAR(); LGKM0(); MFMA16(0, 1); SBAR();
    LDA(1, 0); LDB(1, 0);
    LGKM8();
    SBAR(); LGKM0(); MFMA16(0, 0); SBAR();
    LDA(1, 1);
    SBAR(); LGKM0(); MFMA16(1, 0); SBAR();
    LDB(1, 1);
    SBAR(); LGKM0(); MFMA16(1, 1); SBAR();
    LDA(1, 0);
    SBAR(); LGKM0(); MFMA16(0, 1);
  }

  // ---------------- epilogue ----------------
  if (EPI == 0) {
    u16* H = (u16*)OutP;
#pragma unroll
    for (int mh = 0; mh < 2; ++mh)
#pragma unroll
      for (int fi = 0; fi < 4; ++fi) {
        const int row0 = mT * 256 + mh * 128 + wm * 64 + fi * 16 + hi * 4;
#pragma unroll
        for (int nh = 0; nh < 2; ++nh) {
          const int fc = nT * 128 + (nh * 4 + wn) * 16 + rlo;
          const f32x4 g = acc[mh * 4 + fi][nh * 2 + 0];
          const f32x4 u = acc[mh * 4 + fi][nh * 2 + 1];
#pragma unroll
          for (int r = 0; r < 4; ++r) {
            const float gv = g[r];
            const float hv = gv / (1.f + __expf(-gv)) * u[r];
            H[(size_t)(row0 + r) * 11008 + fc] = f2bf(hv);
          }
        }
      }
  } else {
    float* O = (float*)OutP;
#pragma unroll
    for (int mh = 0; mh < 2; ++mh)
#pragma unroll
      for (int fi = 0; fi < 4; ++fi) {
        const int row0 = mT * 256 + mh * 128 + wm * 64 + fi * 16 + hi * 4;
#pragma unroll
        for (int nh = 0; nh < 2; ++nh)
#pragma unroll
          for (int gi = 0; gi < 2; ++gi) {
            const int col = nT * 256 + nh * 128 + wn * 32 + gi * 16 + rlo;
            const f32x4 a = acc[mh * 4 + fi][nh * 2 + gi];
#pragma unroll
            for (int r = 0; r < 4; ++r)
              O[(size_t)(row0 + r) * 4096 + col] = a[r];
          }
      }
  }
#undef STG_A
#undef STG_B
#undef LDA
#undef LDB
#undef MFMA16
#undef SBAR
#undef LGKM0
#undef LGKM8
#undef VMCNT6
#undef VMCNT0
}

extern "C" void kernel_launch(void* const* d_in, const int* in_sizes, int n_in,
                              void* d_out, int out_size, void* d_ws, size_t ws_size,
                              hipStream_t stream) {
  (void)in_sizes; (void)n_in; (void)out_size; (void)ws_size;
  const float* x  = (const float*)d_in[0];
  const int*   tt = (const int*)d_in[1];
  const float* lg = (const float*)d_in[2];
  const float* lu = (const float*)d_in[3];
  const float* ld = (const float*)d_in[4];
  const float* vg = (const float*)d_in[5];
  const float* vu = (const float*)d_in[6];
  const float* vd = (const float*)d_in[7];

  u16* ws  = (u16*)d_ws;
  u16* xbf = ws;                        // 4096*4096            = 16,777,216
  u16* GUl = xbf + 16777216;            // 22016*4096           = 90,177,536
  u16* GUv = GUl + 90177536;
  u16* ldT = GUv + 90177536;            // 4096*11008           = 45,088,768
  u16* vdT = ldT + 45088768;
  u16* hbuf = vdT + 45088768;           // 4096*11008
  // total: 332,398,592 u16 = ~665 MB

  cvt_x_kernel<<<dim3(8192), dim3(256), 0, stream>>>(x, xbf);
  transpose_cvt_kernel<<<dim3(11008, 6), dim3(256), 0, stream>>>(
      lg, lu, vg, vu, ld, vd, GUl, GUv, ldT, vdT);
  // gate+up fused GEMM: M=4096 (16 mT), N=22016 (86 nT) -> 1376 blocks
  gemm256<8192, 0><<<dim3(1376), dim3(512), 0, stream>>>(xbf, GUl, GUv, tt, hbuf);
  // down GEMM: M=4096, N=4096, K=11008 -> 256 blocks (1/CU)
  gemm256<22016, 1><<<dim3(256), dim3(512), 0, stream>>>(hbuf, ldT, vdT, tt, d_out);
}

// Round 5
// 1308.573 us; speedup vs baseline: 1.1613x; 1.1265x over previous
//
#include <hip/hip_runtime.h>
#include <math.h>

typedef unsigned short u16;
typedef short s16x8 __attribute__((ext_vector_type(8)));
typedef float f32x4 __attribute__((ext_vector_type(4)));

#define GLOAD16(gp, lp)                                                        \
  __builtin_amdgcn_global_load_lds(                                            \
      (const __attribute__((address_space(1))) void*)(gp),                     \
      (__attribute__((address_space(3))) void*)(lp), 16, 0, 0)

__device__ __forceinline__ u16 f2bf(float f) {
  union { float f; unsigned u; } v; v.f = f;
  unsigned r = v.u + 0x7fffu + ((v.u >> 16) & 1u);  // RNE
  return (u16)(r >> 16);
}

// ---------------- kernel 1: x fp32 -> bf16 ----------------
__global__ __launch_bounds__(256) void cvt_x_kernel(const float* __restrict__ in,
                                                    u16* __restrict__ out) {
  size_t i = ((size_t)blockIdx.x * 256 + threadIdx.x) * 8;
  float4 a = *(const float4*)(in + i);
  float4 b = *(const float4*)(in + i + 4);
  s16x8 v;
  v[0] = (short)f2bf(a.x); v[1] = (short)f2bf(a.y);
  v[2] = (short)f2bf(a.z); v[3] = (short)f2bf(a.w);
  v[4] = (short)f2bf(b.x); v[5] = (short)f2bf(b.y);
  v[6] = (short)f2bf(b.z); v[7] = (short)f2bf(b.w);
  *(s16x8*)(out + i) = v;
}

// ------- kernel 2: transpose+cvt. mats 0-3 (g/u) write into interleaved GU:
// GU row for logical f-col, type t: (f>>4)*32 + t*16 + (f&15). mats 4,5 plain.
__global__ __launch_bounds__(256) void transpose_cvt_kernel(
    const float* __restrict__ in0, const float* __restrict__ in1,
    const float* __restrict__ in2, const float* __restrict__ in3,
    const float* __restrict__ in4, const float* __restrict__ in5,
    u16* __restrict__ o01, u16* __restrict__ o23,
    u16* __restrict__ o4, u16* __restrict__ o5) {
  __shared__ float s[64 * 65];
  const int mat = blockIdx.y;
  const float* in; u16* out;
  switch (mat) {
    case 0: in = in0; out = o01; break;
    case 1: in = in1; out = o01; break;
    case 2: in = in2; out = o23; break;
    case 3: in = in3; out = o23; break;
    case 4: in = in4; out = o4; break;
    default: in = in5; out = o5; break;
  }
  const int R = (mat < 4) ? 4096 : 11008;
  const int C = (mat < 4) ? 11008 : 4096;
  const int nTc = C >> 6;
  const int tr = blockIdx.x / nTc, tc = blockIdx.x - tr * nTc;
  const int r0 = tr << 6, c0 = tc << 6;
  const int t = threadIdx.x;
#pragma unroll
  for (int p = 0; p < 4; ++p) {
    const int lr = p * 16 + (t >> 4);
    const int lc = (t & 15) * 4;
    float4 v = *(const float4*)(in + (size_t)(r0 + lr) * C + (c0 + lc));
    float* sp = &s[lr * 65 + lc];
    sp[0] = v.x; sp[1] = v.y; sp[2] = v.z; sp[3] = v.w;
  }
  __syncthreads();
#pragma unroll
  for (int q = 0; q < 2; ++q) {
    const int oc = q * 32 + (t >> 3);
    const int orr = (t & 7) * 8;
    s16x8 v;
#pragma unroll
    for (int i = 0; i < 8; ++i) v[i] = (short)f2bf(s[(orr + i) * 65 + oc]);
    const int f = c0 + oc;
    size_t orow;
    if (mat < 4) orow = (size_t)((f >> 4) << 5) + ((mat & 1) << 4) + (f & 15);
    else         orow = (size_t)f;
    *(s16x8*)(out + orow * R + (r0 + orr)) = v;
  }
}

// ======== 8-phase 256x256 GEMM, frag-once schedule ==========================
// Quadrants (0,0)(0,1)(1,1)(1,0); bf[2 nh-sets] resident -> each fragment is
// ds_read exactly ONCE (48 b128/iter/wave vs 64). Stage order satisfies
// stage-after-last-read: reads buf0 {A0,B0}@P1 {B1}@P2 {A1}@P3, stages
// A-h1(T+1)@P1, A-h0(T+2)@P2, B-h0@P3, B-h1@P4, A-h1@P5; buf1 mirrored P5-P8
// + next-P1. vmcnt(6) at P4/P8 drains everything except the newest 3 halves.
#define SBAR() __builtin_amdgcn_s_barrier()
#define LGKM0() asm volatile("s_waitcnt lgkmcnt(0)")
#define LGKM8() asm volatile("s_waitcnt lgkmcnt(8)")
#define VMCNT6() asm volatile("s_waitcnt vmcnt(6)")
#define VMCNT0() asm volatile("s_waitcnt vmcnt(0)")

// ---------------- persistent gate+up GEMM + silu fusion ----------------
__global__ __launch_bounds__(512, 1) void gemm_gateup_persist(
    const u16* __restrict__ A, const u16* __restrict__ Bl,
    const u16* __restrict__ Bv, const int* __restrict__ tt,
    u16* __restrict__ H) {
  __shared__ u16 sA[2][2][128][64];
  __shared__ u16 sB[2][2][128][64];

  const int bid = blockIdx.x;
  const int c = ((bid >> 7) << 3) | (bid & 7);
  const int mT = (bid >> 3) & 15;
  const int ntiles = (c < 6) ? 6 : 5;
  const int FK = ntiles * 64;

  const int t = threadIdx.x;
  const int lane = t & 63;
  const int rlo = lane & 15;
  const int hi = lane >> 4;
  const int wn = (t >> 6) & 3;
  const int wm = (t >> 8) & 1;

  const int side = tt[mT << 8];
  const u16* B = side ? Bl : Bv;

  const int rowq = t >> 3;
  const int gsw = ((t & 7) ^ (rowq & 7)) << 4;
  const char* srcA = (const char*)A + (size_t)(mT * 256 + rowq) * 8192 + gsw;
  const char* srcB0 = (const char*)B + ((size_t)(c * 256) + rowq) * 8192 + gsw;
  char* ldsA = (char*)&sA[0][0][0][0];
  char* ldsB = (char*)&sB[0][0][0][0];
  const int woff = (t & 448) << 4;

#define PSTG_A(d, h, q)                                                        \
  do {                                                                         \
    const char* _pa = srcA + ((q) & 63) * 128;                                 \
    GLOAD16(_pa + (size_t)((h) * 128) * 8192,                                  \
            ldsA + (d) * 32768 + (h) * 16384 + woff);                          \
    GLOAD16(_pa + (size_t)((h) * 128 + 64) * 8192,                             \
            ldsA + (d) * 32768 + (h) * 16384 + 8192 + woff);                   \
  } while (0)
#define PSTG_B(d, h, q)                                                        \
  do {                                                                         \
    const char* _pb = srcB0 + (size_t)((q) >> 6) * 33554432 +                  \
                      (size_t)((h) * 128) * 8192 + ((q) & 63) * 128;           \
    GLOAD16(_pb, ldsB + (d) * 32768 + (h) * 16384 + woff);                     \
    GLOAD16(_pb + (size_t)64 * 8192,                                           \
            ldsB + (d) * 32768 + (h) * 16384 + 8192 + woff);                   \
  } while (0)

  const int cxa = (hi ^ (rlo & 7)) << 4;
  const int cxb = ((4 + hi) ^ (rlo & 7)) << 4;
  const int arow = (wm * 64 + rlo) * 128;
  const int brow = (wn * 32 + rlo) * 128;

  s16x8 af[4][2], bf[2][2][2];  // bf[nh-set][gi][ks] resident across P1..P4
  f32x4 acc[8][4];
  const f32x4 z = {0.f, 0.f, 0.f, 0.f};
#pragma unroll
  for (int i = 0; i < 8; ++i)
#pragma unroll
    for (int j = 0; j < 4; ++j) acc[i][j] = z;

#define LDA(d, mh)                                                             \
  do {                                                                         \
    _Pragma("unroll") for (int fi = 0; fi < 4; ++fi) {                         \
      const char* p = ldsA + (d) * 32768 + (mh) * 16384 + arow + fi * 2048;    \
      af[fi][0] = *(const s16x8*)(p + cxa);                                    \
      af[fi][1] = *(const s16x8*)(p + cxb);                                    \
    }                                                                          \
  } while (0)
#define LDBS(bi, d, nh)                                                        \
  do {                                                                         \
    _Pragma("unroll") for (int gi = 0; gi < 2; ++gi) {                         \
      const char* p = ldsB + (d) * 32768 + (nh) * 16384 + brow + gi * 2048;    \
      bf[bi][gi][0] = *(const s16x8*)(p + cxa);                                \
      bf[bi][gi][1] = *(const s16x8*)(p + cxb);                                \
    }                                                                          \
  } while (0)
#define MFMA16(mh, nh)                                                         \
  do {                                                                         \
    __builtin_amdgcn_s_setprio(1);                                             \
    _Pragma("unroll") for (int fi = 0; fi < 4; ++fi)                           \
        _Pragma("unroll") for (int gi = 0; gi < 2; ++gi) {                     \
      acc[(mh)*4 + fi][(nh)*2 + gi] = __builtin_amdgcn_mfma_f32_16x16x32_bf16( \
          af[fi][0], bf[nh][gi][0], acc[(mh)*4 + fi][(nh)*2 + gi], 0, 0, 0);   \
      acc[(mh)*4 + fi][(nh)*2 + gi] = __builtin_amdgcn_mfma_f32_16x16x32_bf16( \
          af[fi][1], bf[nh][gi][1], acc[(mh)*4 + fi][(nh)*2 + gi], 0, 0, 0);   \
    }                                                                          \
    __builtin_amdgcn_s_setprio(0);                                             \
  } while (0)

#define GU_EPI(nTv)                                                            \
  do {                                                                         \
    const int _nT = (nTv);                                                     \
    _Pragma("unroll") for (int mh = 0; mh < 2; ++mh)                           \
        _Pragma("unroll") for (int fi = 0; fi < 4; ++fi) {                     \
      const int row0 = mT * 256 + mh * 128 + wm * 64 + fi * 16 + hi * 4;       \
      _Pragma("unroll") for (int nh = 0; nh < 2; ++nh) {                       \
        const int fc = _nT * 128 + (nh * 4 + wn) * 16 + rlo;                   \
        const f32x4 g = acc[mh * 4 + fi][nh * 2 + 0];                          \
        const f32x4 u = acc[mh * 4 + fi][nh * 2 + 1];                          \
        _Pragma("unroll") for (int r = 0; r < 4; ++r) {                        \
          const float gv = g[r];                                               \
          const float hv = gv / (1.f + __expf(-gv)) * u[r];                    \
          H[(size_t)(row0 + r) * 11008 + fc] = f2bf(hv);                       \
        }                                                                      \
      }                                                                        \
    }                                                                          \
  } while (0)

  // prologue: tile0 full -> buf0; tile1 {A-h0, B-h0, B-h1} -> buf1
  PSTG_A(0, 0, 0); PSTG_B(0, 0, 0); PSTG_B(0, 1, 0); PSTG_A(0, 1, 0);
  PSTG_A(1, 0, 1); PSTG_B(1, 0, 1); PSTG_B(1, 1, 1);
  VMCNT6();
  SBAR();

  for (int T = 0; T < FK - 2; T += 2) {
    // P1: af(mh0), bf0 | stage A-h1(T+1)->buf1
    LDA(0, 0); LDBS(0, 0, 0);
    PSTG_A(1, 1, T + 1);
    LGKM8();
    SBAR(); LGKM0(); MFMA16(0, 0); SBAR();
    // P2: bf1 | stage A-h0(T+2)->buf0
    LDBS(1, 0, 1);
    PSTG_A(0, 0, T + 2);
    SBAR(); LGKM0(); MFMA16(0, 1); SBAR();
    // P3: af(mh1) | stage B-h0(T+2)->buf0
    LDA(0, 1);
    PSTG_B(0, 0, T + 2);
    SBAR(); LGKM0(); MFMA16(1, 1); SBAR();
    // P4: no reads | stage B-h1(T+2)->buf0 | checkpoint
    PSTG_B(0, 1, T + 2);
    VMCNT6();
    SBAR(); MFMA16(1, 0); SBAR();
    // P5: buf1 af(mh0), bf0 | stage A-h1(T+2)->buf0
    LDA(1, 0); LDBS(0, 1, 0);
    PSTG_A(0, 1, T + 2);
    LGKM8();
    SBAR(); LGKM0(); MFMA16(0, 0); SBAR();
    // P6: bf1 | stage A-h0(T+3)->buf1
    LDBS(1, 1, 1);
    PSTG_A(1, 0, T + 3);
    SBAR(); LGKM0(); MFMA16(0, 1); SBAR();
    // P7: af(mh1) | stage B-h0(T+3)->buf1
    LDA(1, 1);
    PSTG_B(1, 0, T + 3);
    SBAR(); LGKM0(); MFMA16(1, 1); SBAR();
    // P8: no reads | stage B-h1(T+3)->buf1 | checkpoint
    PSTG_B(1, 1, T + 3);
    VMCNT6();
    SBAR(); MFMA16(1, 0); SBAR();

    if ((T & 63) == 62) {  // tile (T>>6) complete
      GU_EPI(c + 16 * (T >> 6));
#pragma unroll
      for (int i = 0; i < 8; ++i)
#pragma unroll
        for (int j = 0; j < 4; ++j) acc[i][j] = z;
    }
  }
  // tail pair (tiles FK-2, FK-1): P1 stages the last half; drain at P4
  {
    LDA(0, 0); LDBS(0, 0, 0);
    PSTG_A(1, 1, FK - 1);
    LGKM8();
    SBAR(); LGKM0(); MFMA16(0, 0); SBAR();
    LDBS(1, 0, 1);
    SBAR(); LGKM0(); MFMA16(0, 1); SBAR();
    LDA(0, 1);
    SBAR(); LGKM0(); MFMA16(1, 1); SBAR();
    VMCNT0();
    SBAR(); MFMA16(1, 0); SBAR();
    LDA(1, 0); LDBS(0, 1, 0);
    LGKM8();
    SBAR(); LGKM0(); MFMA16(0, 0); SBAR();
    LDBS(1, 1, 1);
    SBAR(); LGKM0(); MFMA16(0, 1); SBAR();
    LDA(1, 1);
    SBAR(); LGKM0(); MFMA16(1, 1); SBAR();
    MFMA16(1, 0);
  }
  GU_EPI(c + 16 * (ntiles - 1));
#undef PSTG_A
#undef PSTG_B
#undef LDA
#undef LDBS
#undef MFMA16
#undef GU_EPI
}

// ---------------- down GEMM (frag-once schedule, single tile) --------------
__global__ __launch_bounds__(512, 1) void gemm_down(
    const u16* __restrict__ A, const u16* __restrict__ Bl,
    const u16* __restrict__ Bv, const int* __restrict__ tt,
    float* __restrict__ O) {
  constexpr int KB = 22016;
  constexpr int NK = KB / 128;  // 172
  __shared__ u16 sA[2][2][128][64];
  __shared__ u16 sB[2][2][128][64];

  const int bid = blockIdx.x;
  const int wg = (bid & 7) * 32 + (bid >> 3);
  const int mT = wg & 15;
  const int nT = wg >> 4;

  const int t = threadIdx.x;
  const int lane = t & 63;
  const int rlo = lane & 15;
  const int hi = lane >> 4;
  const int wn = (t >> 6) & 3;
  const int wm = (t >> 8) & 1;

  const int side = tt[mT << 8];
  const u16* B = side ? Bl : Bv;

  const int rowq = t >> 3;
  const int gsw = ((t & 7) ^ (rowq & 7)) << 4;
  const char* srcA = (const char*)A + (size_t)(mT * 256 + rowq) * KB + gsw;
  const char* srcB = (const char*)B + (size_t)(nT * 256 + rowq) * KB + gsw;
  char* ldsA = (char*)&sA[0][0][0][0];
  char* ldsB = (char*)&sB[0][0][0][0];
  const int woff = (t & 448) << 4;

#define STG_A(d, h, kt)                                                        \
  do {                                                                         \
    GLOAD16(srcA + (size_t)((h) * 128) * KB + (kt) * 128,                      \
            ldsA + (d) * 32768 + (h) * 16384 + woff);                          \
    GLOAD16(srcA + (size_t)((h) * 128 + 64) * KB + (kt) * 128,                 \
            ldsA + (d) * 32768 + (h) * 16384 + 8192 + woff);                   \
  } while (0)
#define STG_B(d, h, kt)                                                        \
  do {                                                                         \
    GLOAD16(srcB + (size_t)((h) * 128) * KB + (kt) * 128,                      \
            ldsB + (d) * 32768 + (h) * 16384 + woff);                          \
    GLOAD16(srcB + (size_t)((h) * 128 + 64) * KB + (kt) * 128,                 \
            ldsB + (d) * 32768 + (h) * 16384 + 8192 + woff);                   \
  } while (0)

  const int cxa = (hi ^ (rlo & 7)) << 4;
  const int cxb = ((4 + hi) ^ (rlo & 7)) << 4;
  const int arow = (wm * 64 + rlo) * 128;
  const int brow = (wn * 32 + rlo) * 128;

  s16x8 af[4][2], bf[2][2][2];
  f32x4 acc[8][4];
  const f32x4 z = {0.f, 0.f, 0.f, 0.f};
#pragma unroll
  for (int i = 0; i < 8; ++i)
#pragma unroll
    for (int j = 0; j < 4; ++j) acc[i][j] = z;

#define LDA(d, mh)                                                             \
  do {                                                                         \
    _Pragma("unroll") for (int fi = 0; fi < 4; ++fi) {                         \
      const char* p = ldsA + (d) * 32768 + (mh) * 16384 + arow + fi * 2048;    \
      af[fi][0] = *(const s16x8*)(p + cxa);                                    \
      af[fi][1] = *(const s16x8*)(p + cxb);                                    \
    }                                                                          \
  } while (0)
#define LDBS(bi, d, nh)                                                        \
  do {                                                                         \
    _Pragma("unroll") for (int gi = 0; gi < 2; ++gi) {                         \
      const char* p = ldsB + (d) * 32768 + (nh) * 16384 + brow + gi * 2048;    \
      bf[bi][gi][0] = *(const s16x8*)(p + cxa);                                \
      bf[bi][gi][1] = *(const s16x8*)(p + cxb);                                \
    }                                                                          \
  } while (0)
#define MFMA16(mh, nh)                                                         \
  do {                                                                         \
    __builtin_amdgcn_s_setprio(1);                                             \
    _Pragma("unroll") for (int fi = 0; fi < 4; ++fi)                           \
        _Pragma("unroll") for (int gi = 0; gi < 2; ++gi) {                     \
      acc[(mh)*4 + fi][(nh)*2 + gi] = __builtin_amdgcn_mfma_f32_16x16x32_bf16( \
          af[fi][0], bf[nh][gi][0], acc[(mh)*4 + fi][(nh)*2 + gi], 0, 0, 0);   \
      acc[(mh)*4 + fi][(nh)*2 + gi] = __builtin_amdgcn_mfma_f32_16x16x32_bf16( \
          af[fi][1], bf[nh][gi][1], acc[(mh)*4 + fi][(nh)*2 + gi], 0, 0, 0);   \
    }                                                                          \
    __builtin_amdgcn_s_setprio(0);                                             \
  } while (0)

  STG_A(0, 0, 0); STG_B(0, 0, 0); STG_B(0, 1, 0); STG_A(0, 1, 0);
  STG_A(1, 0, 1); STG_B(1, 0, 1); STG_B(1, 1, 1);
  VMCNT6();
  SBAR();

  for (int T = 0; T < NK - 2; T += 2) {
    LDA(0, 0); LDBS(0, 0, 0);
    STG_A(1, 1, T + 1);
    LGKM8();
    SBAR(); LGKM0(); MFMA16(0, 0); SBAR();
    LDBS(1, 0, 1);
    STG_A(0, 0, T + 2);
    SBAR(); LGKM0(); MFMA16(0, 1); SBAR();
    LDA(0, 1);
    STG_B(0, 0, T + 2);
    SBAR(); LGKM0(); MFMA16(1, 1); SBAR();
    STG_B(0, 1, T + 2);
    VMCNT6();
    SBAR(); MFMA16(1, 0); SBAR();
    LDA(1, 0); LDBS(0, 1, 0);
    STG_A(0, 1, T + 2);
    LGKM8();
    SBAR(); LGKM0(); MFMA16(0, 0); SBAR();
    LDBS(1, 1, 1);
    STG_A(1, 0, T + 3);
    SBAR(); LGKM0(); MFMA16(0, 1); SBAR();
    LDA(1, 1);
    STG_B(1, 0, T + 3);
    SBAR(); LGKM0(); MFMA16(1, 1); SBAR();
    STG_B(1, 1, T + 3);
    VMCNT6();
    SBAR(); MFMA16(1, 0); SBAR();
  }
  {
    LDA(0, 0); LDBS(0, 0, 0);
    STG_A(1, 1, NK - 1);
    LGKM8();
    SBAR(); LGKM0(); MFMA16(0, 0); SBAR();
    LDBS(1, 0, 1);
    SBAR(); LGKM0(); MFMA16(0, 1); SBAR();
    LDA(0, 1);
    SBAR(); LGKM0(); MFMA16(1, 1); SBAR();
    VMCNT0();
    SBAR(); MFMA16(1, 0); SBAR();
    LDA(1, 0); LDBS(0, 1, 0);
    LGKM8();
    SBAR(); LGKM0(); MFMA16(0, 0); SBAR();
    LDBS(1, 1, 1);
    SBAR(); LGKM0(); MFMA16(0, 1); SBAR();
    LDA(1, 1);
    SBAR(); LGKM0(); MFMA16(1, 1); SBAR();
    MFMA16(1, 0);
  }

#pragma unroll
  for (int mh = 0; mh < 2; ++mh)
#pragma unroll
    for (int fi = 0; fi < 4; ++fi) {
      const int row0 = mT * 256 + mh * 128 + wm * 64 + fi * 16 + hi * 4;
#pragma unroll
      for (int nh = 0; nh < 2; ++nh)
#pragma unroll
        for (int gi = 0; gi < 2; ++gi) {
          const int col = nT * 256 + nh * 128 + wn * 32 + gi * 16 + rlo;
          const f32x4 a = acc[mh * 4 + fi][nh * 2 + gi];
#pragma unroll
          for (int r = 0; r < 4; ++r)
            O[(size_t)(row0 + r) * 4096 + col] = a[r];
        }
    }
#undef STG_A
#undef STG_B
#undef LDA
#undef LDBS
#undef MFMA16
}

extern "C" void kernel_launch(void* const* d_in, const int* in_sizes, int n_in,
                              void* d_out, int out_size, void* d_ws, size_t ws_size,
                              hipStream_t stream) {
  (void)in_sizes; (void)n_in; (void)out_size; (void)ws_size;
  const float* x  = (const float*)d_in[0];
  const int*   tt = (const int*)d_in[1];
  const float* lg = (const float*)d_in[2];
  const float* lu = (const float*)d_in[3];
  const float* ld = (const float*)d_in[4];
  const float* vg = (const float*)d_in[5];
  const float* vu = (const float*)d_in[6];
  const float* vd = (const float*)d_in[7];

  u16* ws  = (u16*)d_ws;
  u16* xbf = ws;                        // 4096*4096            = 16,777,216
  u16* GUl = xbf + 16777216;            // 22016*4096           = 90,177,536
  u16* GUv = GUl + 90177536;
  u16* ldT = GUv + 90177536;            // 4096*11008           = 45,088,768
  u16* vdT = ldT + 45088768;
  u16* hbuf = vdT + 45088768;           // 4096*11008
  // total: 332,398,592 u16 = ~665 MB

  cvt_x_kernel<<<dim3(8192), dim3(256), 0, stream>>>(x, xbf);
  transpose_cvt_kernel<<<dim3(11008, 6), dim3(256), 0, stream>>>(
      lg, lu, vg, vu, ld, vd, GUl, GUv, ldT, vdT);
  gemm_gateup_persist<<<dim3(256), dim3(512), 0, stream>>>(
      xbf, GUl, GUv, tt, hbuf);
  gemm_down<<<dim3(256), dim3(512), 0, stream>>>(hbuf, ldT, vdT, tt, (float*)d_out);
}